// Round 11
// baseline (134.981 us; speedup 1.0000x reference)
//
#include <hip/hip_runtime.h>
#include <math.h>

#define DD 160
#define HH 192
#define WW 160
#define WTW 16         // per-wave tile width
#define WTH 8          // per-wave tile height (2 h-adjacent voxels/thread)
#define BWX 32         // block tile width  (2 waves across)
#define BWY 16         // block tile height (2 waves down)
#define TD 8
#define HW (HH * WW)
#define NVOX (DD * HW)
#define HTW 18         // halo cols
#define HTH 10         // halo rows
#define LSTR 24        // per-32-lane-phase: all 32 banks exactly once (verified R10)
#define HALO (HTH * HTW)   // 180
#define WBUF (HTH * LSTR)  // 240 floats per [wave][parity][field]

typedef float v2f __attribute__((ext_vector_type(2)));

__device__ __forceinline__ v2f vrcp(v2f a) {
    v2f r;
    r.x = __builtin_amdgcn_rcpf(a.x);
    r.y = __builtin_amdgcn_rcpf(a.y);
    return r;
}

// packed atan: odd minimax poly on [0,1] + rcp range reduction; err ~1e-5 rad
__device__ __forceinline__ v2f atanv(v2f r) {
    v2f ar = __builtin_elementwise_abs(r);
    v2f inv = vrcp(ar);
    v2f x = __builtin_elementwise_min(ar, inv);
    v2f x2 = x * x;
    v2f p = __builtin_elementwise_fma(x2,
            __builtin_elementwise_fma(x2,
            __builtin_elementwise_fma(x2,
            __builtin_elementwise_fma(x2,
            __builtin_elementwise_fma(x2, (v2f)(-0.0117212f), (v2f)(0.05265332f)),
            (v2f)(-0.11643287f)), (v2f)(0.19354346f)), (v2f)(-0.33262347f)),
            (v2f)(0.99997726f));
    p *= x;
    v2f q = 1.57079632679489662f - p;
    v2f res;
    res.x = ar.x > 1.0f ? q.x : p.x;
    res.y = ar.y > 1.0f ? q.y : p.y;
    res.x = copysignf(res.x, r.x);
    res.y = copysignf(res.y, r.y);
    return res;
}

// R10 structure (4 independent waves/block, private LDS pipelines, no
// __syncthreads until final reduce, zero-conflict per-phase bank layout,
// packed fp32) + DISTANCE-2 global prefetch: loads for slice d+1 are issued
// two stages before commit (slack ~1400 cyc > ~1200 cyc loaded-HBM latency),
// for both M/S staging and flow. Two named-scalar sets (A even / B odd
// stages); no launch-bounds cap (R8: caps => spill), unroll 2 (R7 lesson).
__global__ __launch_bounds__(256) void demons_ori_kernel(
    const float* __restrict__ Mv, const float* __restrict__ Sv,
    const float* __restrict__ flow, float* __restrict__ out)
{
    __shared__ float buf[4][2][2][WBUF];   // [wave][parity][field][h*LSTR+w]
    __shared__ float redbuf[4];

    const int tid = threadIdx.x;
    const int wid = tid >> 6;
    const int lane = tid & 63;
    const int tw = lane & 15;
    const int r  = (lane >> 4) * 2;        // thread's first tile row: 0,2,4,6
    const int w0 = blockIdx.x * BWX + (wid & 1) * WTW;
    const int h0 = blockIdx.y * BWY + (wid >> 1) * WTH;
    const int d0 = blockIdx.z * TD;

    // slice-invariant staging slots: lane, lane+64, lane+128 (180 total)
    const bool has2 = (lane < HALO - 128);   // lanes 0..51
    int idx0, idx1, idx2 = 0, gb0, gb1, gb2 = 0;
    bool ok0, ok1, ok2 = false;
    {
        int i = lane;
        int hh = i / HTW, ww = i - HTW * hh;
        int gh = h0 + hh - 1, gw = w0 + ww - 1;
        idx0 = hh * LSTR + ww;
        ok0 = (gh >= 0 && gh < HH && gw >= 0 && gw < WW);
        gb0 = gh * WW + gw;
        i = lane + 64;
        hh = i / HTW; ww = i - HTW * hh;
        gh = h0 + hh - 1; gw = w0 + ww - 1;
        idx1 = hh * LSTR + ww;
        ok1 = (gh >= 0 && gh < HH && gw >= 0 && gw < WW);
        gb1 = gh * WW + gw;
        if (has2) {
            i = lane + 128;
            hh = i / HTW; ww = i - HTW * hh;
            gh = h0 + hh - 1; gw = w0 + ww - 1;
            idx2 = hh * LSTR + ww;
            ok2 = (gh >= 0 && gh < HH && gw >= 0 && gw < WW);
            gb2 = gh * WW + gw;
        }
    }

    // two distance-2 prefetch sets — named scalars only (round-3 lesson)
    float aS0 = 0.f, aM0 = 0.f, aS1 = 0.f, aM1 = 0.f, aS2 = 0.f, aM2 = 0.f;
    float bS0 = 0.f, bM0 = 0.f, bS1 = 0.f, bM1 = 0.f, bS2 = 0.f, bM2 = 0.f;

    auto issueA = [&](int d) {
        const bool din = (d >= 0) && (d < DD);
        const size_t base = (size_t)d * HW;
        aS0 = (din && ok0) ? Sv[base + gb0] : 0.f;
        aM0 = (din && ok0) ? Mv[base + gb0] : 0.f;
        aS1 = (din && ok1) ? Sv[base + gb1] : 0.f;
        aM1 = (din && ok1) ? Mv[base + gb1] : 0.f;
        aS2 = (din && ok2) ? Sv[base + gb2] : 0.f;
        aM2 = (din && ok2) ? Mv[base + gb2] : 0.f;
    };
    auto issueB = [&](int d) {
        const bool din = (d >= 0) && (d < DD);
        const size_t base = (size_t)d * HW;
        bS0 = (din && ok0) ? Sv[base + gb0] : 0.f;
        bM0 = (din && ok0) ? Mv[base + gb0] : 0.f;
        bS1 = (din && ok1) ? Sv[base + gb1] : 0.f;
        bM1 = (din && ok1) ? Mv[base + gb1] : 0.f;
        bS2 = (din && ok2) ? Sv[base + gb2] : 0.f;
        bM2 = (din && ok2) ? Mv[base + gb2] : 0.f;
    };
    auto commitA = [&](int d) {
        float* __restrict__ pS = &buf[wid][d & 1][0][0];
        float* __restrict__ pM = &buf[wid][d & 1][1][0];
        pS[idx0] = aS0;  pM[idx0] = aM0;
        pS[idx1] = aS1;  pM[idx1] = aM1;
        if (has2) { pS[idx2] = aS2; pM[idx2] = aM2; }
    };
    auto commitB = [&](int d) {
        float* __restrict__ pS = &buf[wid][d & 1][0][0];
        float* __restrict__ pM = &buf[wid][d & 1][1][0];
        pS[idx0] = bS0;  pM[idx0] = bM0;
        pS[idx1] = bS1;  pM[idx1] = bM1;
        if (has2) { pS[idx2] = bS2; pM[idx2] = bM2; }
    };

    const int rb = r * LSTR + tw;   // stencil rows r..r+3, cols tw..tw+2
    auto fieldPartials = [&](const float* __restrict__ b,
                             v2f& Px, v2f& Py, v2f& Bq, v2f& Cq) {
        const float* r0 = b + rb;
        const float* r1 = r0 + LSTR;
        const float* r2 = r1 + LSTR;
        const float* r3 = r2 + LSTR;
        float a0 = r0[0], b0 = r0[1], c0 = r0[2];
        float a1 = r1[0], b1 = r1[1], c1 = r1[2];
        float a2 = r2[0], b2 = r2[1], c2 = r2[2];
        float a3 = r3[0], b3 = r3[1], c3 = r3[2];
        float X0 = c0 - a0, X1 = c1 - a1, X2 = c2 - a2, X3 = c3 - a3;
        float W0 = a0 + 2.f * b0 + c0, W1 = a1 + 2.f * b1 + c1;
        float W2 = a2 + 2.f * b2 + c2, W3 = a3 + 2.f * b3 + c3;
        float I0 = a0 + b0 + c0, I1 = a1 + b1 + c1;
        float I2 = a2 + b2 + c2, I3 = a3 + b3 + c3;
        Px = (v2f){X0 + 2.f * X1 + X2, X1 + 2.f * X2 + X3};
        Py = (v2f){W2 - W0, W3 - W1};
        Bq = (v2f){I0 + 2.f * I1 + I2, I1 + 2.f * I2 + I3};
        Cq = (v2f){b1, b2};
    };

    // register ring: named v2f per slice {m,z,p} x field {S,M} x {Px,Py,B,C}
    v2f mSPx, mSPy, mSB, mSC, mMPx, mMPy, mMB, mMC;
    v2f zSPx, zSPy, zSB, zSC, zMPx, zMPy, zMB, zMC;
    v2f pSPx, pSPy, pSB, pSC, pMPx, pMPy, pMB, pMC;

    // ---- warmup: distance-2 pipeline fill (wave-local, no barriers) ----
    issueA(d0 - 1);
    issueB(d0);
    commitA(d0 - 1);          // only long exposed vmcnt wait of the wave
    issueA(d0 + 1);           // consumed at loop dd=0 (commitA)
    fieldPartials(&buf[wid][(d0 - 1) & 1][0][0], mSPx, mSPy, mSB, mSC);
    fieldPartials(&buf[wid][(d0 - 1) & 1][1][0], mMPx, mMPy, mMB, mMC);
    commitB(d0);
    issueB(d0 + 2);           // consumed at loop dd=1 (commitB)
    fieldPartials(&buf[wid][d0 & 1][0][0], zSPx, zSPy, zSB, zSC);
    fieldPartials(&buf[wid][d0 & 1][1][0], zMPx, zMPy, zMB, zMC);

    const size_t voffA = (size_t)(h0 + r) * WW + (w0 + tw);   // voxel A; B = +WW
    // flow prefetch: set A for even dd, set B for odd dd (distance 2)
    v2f fAx, fAy, fAz, fBx, fBy, fBz;
    {
        size_t o = (size_t)d0 * HW + voffA;
        fAx = (v2f){flow[o], flow[o + WW]};
        fAy = (v2f){flow[NVOX + o], flow[NVOX + o + WW]};
        fAz = (v2f){flow[2 * (size_t)NVOX + o], flow[2 * (size_t)NVOX + o + WW]};
        o += HW;
        fBx = (v2f){flow[o], flow[o + WW]};
        fBy = (v2f){flow[NVOX + o], flow[NVOX + o + WW]};
        fBz = (v2f){flow[2 * (size_t)NVOX + o], flow[2 * (size_t)NVOX + o + WW]};
    }

    v2f vsum = (v2f){0.f, 0.f};

    #pragma unroll 2
    for (int dd = 0; dd < TD; ++dd) {
        const int d = d0 + dd;
        // commit loads issued 2 stages ago; re-issue same set for slice d+3
        if ((dd & 1) == 0) {
            commitA(d + 1);
            if (dd < TD - 2) issueA(d + 3);
        } else {
            commitB(d + 1);
            if (dd < TD - 2) issueB(d + 3);
        }
        fieldPartials(&buf[wid][(d + 1) & 1][0][0], pSPx, pSPy, pSB, pSC);
        fieldPartials(&buf[wid][(d + 1) & 1][1][0], pMPx, pMPy, pMB, pMC);

        v2f idf = zMC - zSC;
        v2f i2  = __builtin_elementwise_fma(idf, idf, (v2f)(1e-10f));
        v2f gxS = mSPx + zSPx + pSPx;
        v2f gyS = mSPy + zSPy + pSPy;
        v2f gzS = pSB - mSB;
        v2f gxM = mMPx + zMPx + pMPx;
        v2f gyM = mMPy + zMPy + pMPy;
        v2f gzM = pMB - mMB;
        v2f denS = __builtin_elementwise_fma(gxS, gxS,
                   __builtin_elementwise_fma(gyS, gyS,
                   __builtin_elementwise_fma(gzS, gzS, i2)));
        v2f denM = __builtin_elementwise_fma(gxM, gxM,
                   __builtin_elementwise_fma(gyM, gyM,
                   __builtin_elementwise_fma(gzM, gzM, i2)));
        v2f rS = vrcp(denS);
        v2f rM = vrcp(denM);
        v2f Ux = idf * __builtin_elementwise_fma(gxS, rS, gxM * rM);
        v2f Uy = idf * __builtin_elementwise_fma(gyS, rS, gyM * rM);
        v2f Uz = idf * __builtin_elementwise_fma(gzS, rS, gzM * rM);
        v2f rz = vrcp(Uz + 1e-10f);
        v2f dxz = atanv(Ux * rz);
        v2f dyz = atanv(Uy * rz);

        v2f ffx = (dd & 1) ? fBx : fAx;
        v2f ffy = (dd & 1) ? fBy : fAy;
        v2f ffz = (dd & 1) ? fBz : fAz;
        v2f rf = vrcp(ffz + 1e-10f);
        v2f fxz = atanv(ffx * rf);
        v2f fyz = atanv(ffy * rf);

        v2f e1 = fxz - dxz;
        v2f e2 = fyz - dyz;
        vsum = __builtin_elementwise_fma(e1, e1,
               __builtin_elementwise_fma(e2, e2, vsum));

        // reload the just-consumed flow set for slice d+2 (used at dd+2)
        if (dd < TD - 2) {
            size_t o = (size_t)(d + 2) * HW + voffA;
            if ((dd & 1) == 0) {
                fAx = (v2f){flow[o], flow[o + WW]};
                fAy = (v2f){flow[NVOX + o], flow[NVOX + o + WW]};
                fAz = (v2f){flow[2 * (size_t)NVOX + o], flow[2 * (size_t)NVOX + o + WW]};
            } else {
                fBx = (v2f){flow[o], flow[o + WW]};
                fBy = (v2f){flow[NVOX + o], flow[NVOX + o + WW]};
                fBz = (v2f){flow[2 * (size_t)NVOX + o], flow[2 * (size_t)NVOX + o + WW]};
            }
        }

        mSPx = zSPx; mSPy = zSPy; mSB = zSB; mSC = zSC;
        mMPx = zMPx; mMPy = zMPy; mMB = zMB; mMC = zMC;
        zSPx = pSPx; zSPy = pSPy; zSB = pSB; zSC = pSC;
        zMPx = pMPx; zMPy = pMPy; zMB = pMB; zMC = pMC;
    }

    float lsum = vsum.x + vsum.y;
    // wave shuffle reduce -> per-wave LDS slot -> ONE barrier -> one atomic
    #pragma unroll
    for (int o = 32; o > 0; o >>= 1)
        lsum += __shfl_down(lsum, o, 64);
    if (lane == 0)
        redbuf[wid] = lsum;
    __syncthreads();
    if (tid == 0) {
        float s = redbuf[0] + redbuf[1] + redbuf[2] + redbuf[3];
        atomicAdd(out, s * (1.0f / (float)NVOX));
    }
}

extern "C" void kernel_launch(void* const* d_in, const int* in_sizes, int n_in,
                              void* d_out, int out_size, void* d_ws, size_t ws_size,
                              hipStream_t stream) {
    const float* Mv   = (const float*)d_in[0];
    const float* Sv   = (const float*)d_in[1];
    const float* flow = (const float*)d_in[2];
    float* out = (float*)d_out;

    hipMemsetAsync(out, 0, sizeof(float), stream);

    dim3 grid(WW / BWX, HH / BWY, DD / TD);   // 5 x 12 x 20 = 1200 blocks
    demons_ori_kernel<<<grid, dim3(256), 0, stream>>>(Mv, Sv, flow, out);
}

// Round 12
// 133.589 us; speedup vs baseline: 1.0104x; 1.0104x over previous
//
#include <hip/hip_runtime.h>
#include <math.h>

#define DD 160
#define HH 192
#define WW 160
#define WTW 16         // per-wave tile width
#define WTH 8          // per-wave tile height (2 h-adjacent voxels/thread)
#define BWX 32         // block tile width  (2 waves across)
#define BWY 16         // block tile height (2 waves down)
#define TD 8
#define HW (HH * WW)
#define NVOX (DD * HW)
#define HTW 18         // halo cols
#define HTH 10         // halo rows
#define LSTR 24        // per-32-lane-phase: all 32 banks exactly once (verified R10)
#define HALO (HTH * HTW)   // 180
#define WBUF (HTH * LSTR)  // 240 floats per [wave][parity][field]

typedef float v2f __attribute__((ext_vector_type(2)));

__device__ __forceinline__ v2f vrcp(v2f a) {
    v2f r;
    r.x = __builtin_amdgcn_rcpf(a.x);
    r.y = __builtin_amdgcn_rcpf(a.y);
    return r;
}

// packed atan: odd minimax poly on [0,1] + rcp range reduction; err ~1e-5 rad
__device__ __forceinline__ v2f atanv(v2f r) {
    v2f ar = __builtin_elementwise_abs(r);
    v2f inv = vrcp(ar);
    v2f x = __builtin_elementwise_min(ar, inv);
    v2f x2 = x * x;
    v2f p = __builtin_elementwise_fma(x2,
            __builtin_elementwise_fma(x2,
            __builtin_elementwise_fma(x2,
            __builtin_elementwise_fma(x2,
            __builtin_elementwise_fma(x2, (v2f)(-0.0117212f), (v2f)(0.05265332f)),
            (v2f)(-0.11643287f)), (v2f)(0.19354346f)), (v2f)(-0.33262347f)),
            (v2f)(0.99997726f));
    p *= x;
    v2f q = 1.57079632679489662f - p;
    v2f res;
    res.x = ar.x > 1.0f ? q.x : p.x;
    res.y = ar.y > 1.0f ? q.y : p.y;
    res.x = copysignf(res.x, r.x);
    res.y = copysignf(res.y, r.y);
    return res;
}

// R10 base (4 independent waves/block, private LDS, no __syncthreads in main
// loop, per-phase zero-conflict banks, packed fp32, distance-1 prefetch,
// VGPR ~64) + CROSS-STAGE PARITY SHIFT: stage dd writes slice d+2 into
// parity d&1 while reading slice d+1's partials from parity (d+1)&1 written
// at stage dd-1 — the in-stage ds_write->ds_read RAW (R10/R11's exposed
// ~200 cyc LDS latency per stage) is gone; writes retire in the shadow.
__global__ __launch_bounds__(256) void demons_ori_kernel(
    const float* __restrict__ Mv, const float* __restrict__ Sv,
    const float* __restrict__ flow, float* __restrict__ out)
{
    __shared__ float buf[4][2][2][WBUF];   // [wave][parity][field][h*LSTR+w]
    __shared__ float redbuf[4];

    const int tid = threadIdx.x;
    const int wid = tid >> 6;
    const int lane = tid & 63;
    const int tw = lane & 15;
    const int r  = (lane >> 4) * 2;        // thread's first tile row: 0,2,4,6
    const int w0 = blockIdx.x * BWX + (wid & 1) * WTW;
    const int h0 = blockIdx.y * BWY + (wid >> 1) * WTH;
    const int d0 = blockIdx.z * TD;

    // slice-invariant staging slots: lane, lane+64, lane+128 (180 total)
    const bool has2 = (lane < HALO - 128);   // lanes 0..51
    int idx0, idx1, idx2 = 0, gb0, gb1, gb2 = 0;
    bool ok0, ok1, ok2 = false;
    {
        int i = lane;
        int hh = i / HTW, ww = i - HTW * hh;
        int gh = h0 + hh - 1, gw = w0 + ww - 1;
        idx0 = hh * LSTR + ww;
        ok0 = (gh >= 0 && gh < HH && gw >= 0 && gw < WW);
        gb0 = gh * WW + gw;
        i = lane + 64;
        hh = i / HTW; ww = i - HTW * hh;
        gh = h0 + hh - 1; gw = w0 + ww - 1;
        idx1 = hh * LSTR + ww;
        ok1 = (gh >= 0 && gh < HH && gw >= 0 && gw < WW);
        gb1 = gh * WW + gw;
        if (has2) {
            i = lane + 128;
            hh = i / HTW; ww = i - HTW * hh;
            gh = h0 + hh - 1; gw = w0 + ww - 1;
            idx2 = hh * LSTR + ww;
            ok2 = (gh >= 0 && gh < HH && gw >= 0 && gw < WW);
            gb2 = gh * WW + gw;
        }
    }

    // distance-1 prefetch set — named scalars only (round-3 lesson)
    float pS0 = 0.f, pM0 = 0.f, pS1 = 0.f, pM1 = 0.f, pS2 = 0.f, pM2 = 0.f;

    auto issue = [&](int d) {
        const bool din = (d >= 0) && (d < DD);
        const size_t base = (size_t)d * HW;
        pS0 = (din && ok0) ? Sv[base + gb0] : 0.f;
        pM0 = (din && ok0) ? Mv[base + gb0] : 0.f;
        pS1 = (din && ok1) ? Sv[base + gb1] : 0.f;
        pM1 = (din && ok1) ? Mv[base + gb1] : 0.f;
        pS2 = (din && ok2) ? Sv[base + gb2] : 0.f;
        pM2 = (din && ok2) ? Mv[base + gb2] : 0.f;
    };
    auto commit = [&](int d) {
        float* __restrict__ bS = &buf[wid][d & 1][0][0];
        float* __restrict__ bM = &buf[wid][d & 1][1][0];
        bS[idx0] = pS0;  bM[idx0] = pM0;
        bS[idx1] = pS1;  bM[idx1] = pM1;
        if (has2) { bS[idx2] = pS2; bM[idx2] = pM2; }
    };

    const int rb = r * LSTR + tw;   // stencil rows r..r+3, cols tw..tw+2
    auto fieldPartials = [&](const float* __restrict__ b,
                             v2f& Px, v2f& Py, v2f& Bq, v2f& Cq) {
        const float* r0 = b + rb;
        const float* r1 = r0 + LSTR;
        const float* r2 = r1 + LSTR;
        const float* r3 = r2 + LSTR;
        float a0 = r0[0], b0 = r0[1], c0 = r0[2];
        float a1 = r1[0], b1 = r1[1], c1 = r1[2];
        float a2 = r2[0], b2 = r2[1], c2 = r2[2];
        float a3 = r3[0], b3 = r3[1], c3 = r3[2];
        float X0 = c0 - a0, X1 = c1 - a1, X2 = c2 - a2, X3 = c3 - a3;
        float W0 = a0 + 2.f * b0 + c0, W1 = a1 + 2.f * b1 + c1;
        float W2 = a2 + 2.f * b2 + c2, W3 = a3 + 2.f * b3 + c3;
        float I0 = a0 + b0 + c0, I1 = a1 + b1 + c1;
        float I2 = a2 + b2 + c2, I3 = a3 + b3 + c3;
        Px = (v2f){X0 + 2.f * X1 + X2, X1 + 2.f * X2 + X3};
        Py = (v2f){W2 - W0, W3 - W1};
        Bq = (v2f){I0 + 2.f * I1 + I2, I1 + 2.f * I2 + I3};
        Cq = (v2f){b1, b2};
    };

    // register ring: named v2f per slice {m,z,p} x field {S,M} x {Px,Py,B,C}
    v2f mSPx, mSPy, mSB, mSC, mMPx, mMPy, mMB, mMC;
    v2f zSPx, zSPy, zSB, zSC, zMPx, zMPy, zMB, zMC;
    v2f pSPx, pSPy, pSB, pSC, pMPx, pMPy, pMB, pMC;

    // ---- warmup: fill parities for d0-1, d0, d0+1; partials for d0-1, d0.
    // The two warmup partials have a write->read RAW (once, acceptable).
    issue(d0 - 1);
    commit(d0 - 1);
    issue(d0);
    fieldPartials(&buf[wid][(d0 - 1) & 1][0][0], mSPx, mSPy, mSB, mSC);
    fieldPartials(&buf[wid][(d0 - 1) & 1][1][0], mMPx, mMPy, mMB, mMC);
    commit(d0);
    issue(d0 + 1);
    fieldPartials(&buf[wid][d0 & 1][0][0], zSPx, zSPy, zSB, zSC);
    fieldPartials(&buf[wid][d0 & 1][1][0], zMPx, zMPy, zMB, zMC);
    commit(d0 + 1);          // parity (d0+1)&1 — read in loop dd=0 (no RAW there)
    issue(d0 + 2);           // committed in loop dd=0

    const size_t voffA = (size_t)(h0 + r) * WW + (w0 + tw);   // voxel A; B = +WW
    v2f fFx, fFy, fFz;
    {
        size_t o = (size_t)d0 * HW + voffA;
        fFx = (v2f){flow[o], flow[o + WW]};
        fFy = (v2f){flow[NVOX + o], flow[NVOX + o + WW]};
        fFz = (v2f){flow[2 * (size_t)NVOX + o], flow[2 * (size_t)NVOX + o + WW]};
    }

    v2f vsum = (v2f){0.f, 0.f};

    #pragma unroll 2
    for (int dd = 0; dd < TD; ++dd) {
        const int d = d0 + dd;
        // write slice d+2 into parity d&1 (slice d's raw there is dead);
        // loads for it were issued one stage ago — vmcnt slack ~1 stage.
        if (dd < TD - 1) commit(d + 2);
        if (dd < TD - 2) issue(d + 3);
        v2f nFx = (v2f){0.f, 0.f}, nFy = nFx, nFz = nFx;
        if (dd < TD - 1) {
            size_t o = (size_t)(d + 1) * HW + voffA;
            nFx = (v2f){flow[o], flow[o + WW]};
            nFy = (v2f){flow[NVOX + o], flow[NVOX + o + WW]};
            nFz = (v2f){flow[2 * (size_t)NVOX + o], flow[2 * (size_t)NVOX + o + WW]};
        }
        // partials for slice d+1 from parity (d+1)&1 — written at stage dd-1
        // (warmup for dd=0): no dependency on this stage's ds_writes.
        fieldPartials(&buf[wid][(d + 1) & 1][0][0], pSPx, pSPy, pSB, pSC);
        fieldPartials(&buf[wid][(d + 1) & 1][1][0], pMPx, pMPy, pMB, pMC);

        v2f idf = zMC - zSC;
        v2f i2  = __builtin_elementwise_fma(idf, idf, (v2f)(1e-10f));
        v2f gxS = mSPx + zSPx + pSPx;
        v2f gyS = mSPy + zSPy + pSPy;
        v2f gzS = pSB - mSB;
        v2f gxM = mMPx + zMPx + pMPx;
        v2f gyM = mMPy + zMPy + pMPy;
        v2f gzM = pMB - mMB;
        v2f denS = __builtin_elementwise_fma(gxS, gxS,
                   __builtin_elementwise_fma(gyS, gyS,
                   __builtin_elementwise_fma(gzS, gzS, i2)));
        v2f denM = __builtin_elementwise_fma(gxM, gxM,
                   __builtin_elementwise_fma(gyM, gyM,
                   __builtin_elementwise_fma(gzM, gzM, i2)));
        v2f rS = vrcp(denS);
        v2f rM = vrcp(denM);
        v2f Ux = idf * __builtin_elementwise_fma(gxS, rS, gxM * rM);
        v2f Uy = idf * __builtin_elementwise_fma(gyS, rS, gyM * rM);
        v2f Uz = idf * __builtin_elementwise_fma(gzS, rS, gzM * rM);
        v2f rz = vrcp(Uz + 1e-10f);
        v2f dxz = atanv(Ux * rz);
        v2f dyz = atanv(Uy * rz);

        v2f rf = vrcp(fFz + 1e-10f);
        v2f fxz = atanv(fFx * rf);
        v2f fyz = atanv(fFy * rf);

        v2f e1 = fxz - dxz;
        v2f e2 = fyz - dyz;
        vsum = __builtin_elementwise_fma(e1, e1,
               __builtin_elementwise_fma(e2, e2, vsum));

        mSPx = zSPx; mSPy = zSPy; mSB = zSB; mSC = zSC;
        mMPx = zMPx; mMPy = zMPy; mMB = zMB; mMC = zMC;
        zSPx = pSPx; zSPy = pSPy; zSB = pSB; zSC = pSC;
        zMPx = pMPx; zMPy = pMPy; zMB = pMB; zMC = pMC;
        fFx = nFx; fFy = nFy; fFz = nFz;
    }

    float lsum = vsum.x + vsum.y;
    // wave shuffle reduce -> per-wave LDS slot -> ONE barrier -> one atomic
    #pragma unroll
    for (int o = 32; o > 0; o >>= 1)
        lsum += __shfl_down(lsum, o, 64);
    if (lane == 0)
        redbuf[wid] = lsum;
    __syncthreads();
    if (tid == 0) {
        float s = redbuf[0] + redbuf[1] + redbuf[2] + redbuf[3];
        atomicAdd(out, s * (1.0f / (float)NVOX));
    }
}

extern "C" void kernel_launch(void* const* d_in, const int* in_sizes, int n_in,
                              void* d_out, int out_size, void* d_ws, size_t ws_size,
                              hipStream_t stream) {
    const float* Mv   = (const float*)d_in[0];
    const float* Sv   = (const float*)d_in[1];
    const float* flow = (const float*)d_in[2];
    float* out = (float*)d_out;

    hipMemsetAsync(out, 0, sizeof(float), stream);

    dim3 grid(WW / BWX, HH / BWY, DD / TD);   // 5 x 12 x 20 = 1200 blocks
    demons_ori_kernel<<<grid, dim3(256), 0, stream>>>(Mv, Sv, flow, out);
}